// Round 19
// baseline (517.119 us; speedup 1.0000x reference)
//
#include <hip/hip_runtime.h>
#include <hip/hip_fp16.h>
#include <math.h>

#define N_TOK 4096
#define S_LEN 2048
#define H_DIM 1024
#define E_EXP 8
#define CAPV  1536
#define NHEAD 8
#define HDHD  128

#define SCRATCH_F4 2129920u
#define TOTAL_F4   25165824u

typedef __attribute__((ext_vector_type(8))) _Float16 v8h;
typedef __attribute__((ext_vector_type(4))) float v4f;

__device__ __forceinline__ void splitf16(float v, unsigned short& h, unsigned short& l) {
    __half hh = __float2half(v);
    h = __half_as_ushort(hh);
    l = __half_as_ushort(__float2half(v - __half2float(hh)));
}

__device__ __forceinline__ void gld_lds16(const void* g, void* l) {
    __builtin_amdgcn_global_load_lds(
        (const __attribute__((address_space(1))) unsigned int*)g,
        (__attribute__((address_space(3))) unsigned int*)l,
        16, 0, 0);
}

struct WBatch {
    const float* src[7];
    unsigned short* dh[7];
    unsigned short* dl[7];
};

// ---------------------------------------------------------------- merged prep + weight conversion
__global__ __launch_bounds__(256) void prep_wconv_k(
    const float* __restrict__ hid, unsigned short* __restrict__ hi,
    unsigned short* __restrict__ lo,
    const float* __restrict__ Ws1, const float* __restrict__ bs1,
    const float* __restrict__ Ws2, const float* __restrict__ bs2,
    float* __restrict__ seasons, float* __restrict__ seas24,
    const float* __restrict__ Wr2, float* __restrict__ wr2t, WBatch wb) {
    __shared__ unsigned short Hs[64][65];
    __shared__ unsigned short Ls[64][65];
    int blk = blockIdx.x;
    int tid = threadIdx.x;
    if (blk < 4096) {
        int i = blk * 256 + tid;
        float4 v = ((const float4*)hid)[i];
        ushort4 h, l;
        splitf16(v.x, h.x, l.x);
        splitf16(v.y, h.y, l.y);
        splitf16(v.z, h.z, l.z);
        splitf16(v.w, h.w, l.w);
        ((ushort4*)hi)[i] = h;
        ((ushort4*)lo)[i] = l;
    } else if (blk < 4104) {
        int s = (blk - 4096) * 256 + tid;
        if (s < S_LEN) {
            double a = (double)s * 2.0 * M_PI / 24.0;
            seasons[s] = (float)sin(a);
        }
    } else if (blk < 4128) {
        float* hbuf = (float*)Hs;
        int m = blk - 4104;
        double a = (double)m * 2.0 * M_PI / 24.0;
        float sv = (float)sin(a);
        int j = tid;
        hbuf[j] = fmaxf(sv * Ws1[j] + bs1[j], 0.f);
        __syncthreads();
        float acc = bs2[j];
        for (int i = 0; i < 256; ++i) acc = fmaf(hbuf[i], Ws2[i * 256 + j], acc);
        seas24[m * 256 + j] = acc;
    } else if (blk < 4160) {
        int i = (blk - 4128) * 256 + tid;
        int k = i >> 3, e = i & 7;
        wr2t[e * 1024 + k] = Wr2[i];
    } else {
        int i2 = blk - 4160;
        int wi = i2 >> 8;
        int rem = i2 & 255;
        int k0 = (rem >> 4) << 6, n0 = (rem & 15) << 6;
        const float* __restrict__ W = wb.src[wi];
        unsigned short* __restrict__ Thi = wb.dh[wi];
        unsigned short* __restrict__ Tlo = wb.dl[wi];
#pragma unroll
        for (int i = 0; i < 4; ++i) {
            int idx = tid + i * 256;
            int kk = idx >> 4, n4 = idx & 15;
            float4 v = *(const float4*)(W + (size_t)(k0 + kk) * 1024 + n0 + n4 * 4);
            unsigned short h, l;
            splitf16(v.x, h, l); Hs[n4 * 4 + 0][kk] = h; Ls[n4 * 4 + 0][kk] = l;
            splitf16(v.y, h, l); Hs[n4 * 4 + 1][kk] = h; Ls[n4 * 4 + 1][kk] = l;
            splitf16(v.z, h, l); Hs[n4 * 4 + 2][kk] = h; Ls[n4 * 4 + 2][kk] = l;
            splitf16(v.w, h, l); Hs[n4 * 4 + 3][kk] = h; Ls[n4 * 4 + 3][kk] = l;
        }
        __syncthreads();
#pragma unroll
        for (int i = 0; i < 4; ++i) {
            int idx = tid + i * 256;
            int n = idx >> 4, k4 = idx & 15;
            ushort4 h = make_ushort4(Hs[n][k4 * 4], Hs[n][k4 * 4 + 1], Hs[n][k4 * 4 + 2], Hs[n][k4 * 4 + 3]);
            ushort4 l = make_ushort4(Ls[n][k4 * 4], Ls[n][k4 * 4 + 1], Ls[n][k4 * 4 + 2], Ls[n][k4 * 4 + 3]);
            *(ushort4*)(Thi + (size_t)(n0 + n) * 1024 + k0 + k4 * 4) = h;
            *(ushort4*)(Tlo + (size_t)(n0 + n) * 1024 + k0 + k4 * 4) = l;
        }
    }
}

// ---------------------------------------------------------------- co-scheduled fill body
__device__ __forceinline__ void fill_body(float* __restrict__ p, size_t f40, size_t f41, int nblk) {
    v4f z = {0.f, 0.f, 0.f, 0.f};
    v4f* o = (v4f*)p;
    size_t n = f41 - f40;
    size_t T = blockDim.x;
    for (size_t i = (size_t)blockIdx.x * T + threadIdx.x; i < n; i += (size_t)nblk * T)
        __builtin_nontemporal_store(z, o + f40 + i);
}

// ---------------------------------------------------------------- split-f16 MFMA GEMM
// 128x128 tile, 512 threads = 8 waves (4M x 2N), 32x64/wave, BK=32, dbuf, XCD swizzle.
template <int MODE, int EMITF, int EMITS, int FILLN>
__global__ __launch_bounds__(512, 4) void gemm_split(
    const unsigned short* __restrict__ Ahi, const unsigned short* __restrict__ Alo,
    const unsigned short* __restrict__ WThi, const unsigned short* __restrict__ WTlo,
    const float* __restrict__ bias, float* __restrict__ Cf,
    unsigned short* __restrict__ Chi, unsigned short* __restrict__ Clo,
    const float* __restrict__ rowT, const float* __restrict__ rowS,
    const float* __restrict__ seasons, const float* __restrict__ pos,
    const float* __restrict__ seas24, float escale, float* __restrict__ fillp) {
    if (FILLN > 0) {
        if (blockIdx.x < (unsigned)FILLN) {
            fill_body(fillp, 0, SCRATCH_F4, FILLN);
            return;
        }
    }
    __shared__ unsigned short Ash[2][128 * 32];
    __shared__ unsigned short Asl[2][128 * 32];
    __shared__ unsigned short Bsh[2][128 * 32];
    __shared__ unsigned short Bsl[2][128 * 32];
    int tid = threadIdx.x;
    int lane = tid & 63, w = tid >> 6;
    int l15 = lane & 15, l16 = lane >> 4;
    int wm = (w >> 1) * 32, wn = (w & 1) * 64;

    int bid = blockIdx.x - FILLN;
    int mp = (bid & 7) + ((bid >> 6) << 3);
    int np = (bid >> 3) & 7;
    int m0 = mp * 128, n0 = np * 128;

    int ac0 = tid;
    int ar0 = ac0 >> 2;
    size_t a_src0 = (size_t)(m0 + ar0) * 1024 + (((ac0 & 3) ^ (ar0 & 3)) * 8);
    size_t b_src0 = (size_t)(n0 + ar0) * 1024 + (((ac0 & 3) ^ (ar0 & 3)) * 8);

    int a_off[2], b_off[4];
#pragma unroll
    for (int mi = 0; mi < 2; ++mi) {
        int row = wm + mi * 16 + l15;
        a_off[mi] = row * 32 + ((l16 ^ (row & 3)) * 8);
    }
#pragma unroll
    for (int ni = 0; ni < 4; ++ni) {
        int n = wn + ni * 16 + l15;
        b_off[ni] = n * 32 + ((l16 ^ (n & 3)) * 8);
    }

    auto STAGE = [&](int buf, int k0) {
        gld_lds16(Ahi + a_src0 + k0, &Ash[buf][ac0 * 8]);
        gld_lds16(Alo + a_src0 + k0, &Asl[buf][ac0 * 8]);
        gld_lds16(WThi + b_src0 + k0, &Bsh[buf][ac0 * 8]);
        gld_lds16(WTlo + b_src0 + k0, &Bsl[buf][ac0 * 8]);
    };

    v4f acc[2][4] = {};
    STAGE(0, 0);
    __syncthreads();

    for (int kk = 0; kk < 32; ++kk) {
        int cur = kk & 1;
        if (kk < 31) STAGE(cur ^ 1, (kk + 1) * 32);
        v8h ah[2], al[2], bh[4], bl[4];
#pragma unroll
        for (int mi = 0; mi < 2; ++mi) {
            ah[mi] = *(const v8h*)&Ash[cur][a_off[mi]];
            al[mi] = *(const v8h*)&Asl[cur][a_off[mi]];
        }
#pragma unroll
        for (int ni = 0; ni < 4; ++ni) {
            bh[ni] = *(const v8h*)&Bsh[cur][b_off[ni]];
            bl[ni] = *(const v8h*)&Bsl[cur][b_off[ni]];
        }
#pragma unroll
        for (int mi = 0; mi < 2; ++mi)
#pragma unroll
            for (int ni = 0; ni < 4; ++ni) {
                acc[mi][ni] = __builtin_amdgcn_mfma_f32_16x16x32_f16(ah[mi], bh[ni], acc[mi][ni], 0, 0, 0);
                acc[mi][ni] = __builtin_amdgcn_mfma_f32_16x16x32_f16(al[mi], bh[ni], acc[mi][ni], 0, 0, 0);
                acc[mi][ni] = __builtin_amdgcn_mfma_f32_16x16x32_f16(ah[mi], bl[ni], acc[mi][ni], 0, 0, 0);
            }
        __syncthreads();
    }

#pragma unroll
    for (int mi = 0; mi < 2; ++mi) {
#pragma unroll
        for (int r = 0; r < 4; ++r) {
            int row = m0 + wm + mi * 16 + l16 * 4 + r;
            int s = row & (S_LEN - 1);
            float tval = 0.f, seval = 0.f;
            if (MODE == 1) { tval = (float)s; seval = seasons[s]; }
#pragma unroll
            for (int ni = 0; ni < 4; ++ni) {
                int col = n0 + wn + ni * 16 + l15;
                float v = acc[mi][ni][r] + bias[col];
                if (MODE == 1) v += tval * rowT[col] + seval * rowS[col];
                if (MODE == 2) v += pos[(size_t)s * 1024 + col] + seas24[(s % 24) * 256 + (col & 255)];
                if (MODE == 1 || MODE == 3) v = fmaxf(v, 0.f);
                size_t o = (size_t)row * 1024 + col;
                if (EMITF) Cf[o] = v;
                if (EMITS) {
                    unsigned short hu, lu;
                    splitf16(v * escale, hu, lu);
                    Chi[o] = hu; Clo[o] = lu;
                }
            }
        }
    }
}

// ---------------------------------------------------------------- fused QKV GEMM + co-scheduled big fill
#define NFILLQ 128
__global__ __launch_bounds__(512, 4) void gemm_qkv(
    const unsigned short* __restrict__ Ahi, const unsigned short* __restrict__ Alo,
    const unsigned short* __restrict__ WT3hi, const unsigned short* __restrict__ WT3lo,
    const float* __restrict__ bq, const float* __restrict__ bk,
    const float* __restrict__ bv,
    unsigned short* __restrict__ Qhi, unsigned short* __restrict__ Qlo,
    unsigned short* __restrict__ Khi, unsigned short* __restrict__ Klo,
    unsigned short* __restrict__ VThi, unsigned short* __restrict__ VTlo,
    float qscale, float* __restrict__ fillp) {
    if (blockIdx.x < NFILLQ) {
        fill_body(fillp, SCRATCH_F4, TOTAL_F4, NFILLQ);
        return;
    }
    __shared__ unsigned short Ash[2][128 * 32];
    __shared__ unsigned short Asl[2][128 * 32];
    __shared__ unsigned short Bsh[2][128 * 32];
    __shared__ unsigned short Bsl[2][128 * 32];
    int tid = threadIdx.x;
    int lane = tid & 63, w = tid >> 6;
    int l15 = lane & 15, l16 = lane >> 4;
    int wm = (w >> 1) * 32, wn = (w & 1) * 64;

    int bid = blockIdx.x - NFILLQ;
    int t = bid >> 3;
    int np = t % 24;
    int mp = (bid & 7) + (t / 24) * 8;
    int m0 = mp * 128;
    int wn0 = np * 128;

    int ac0 = tid;
    int ar0 = ac0 >> 2;
    size_t a_src0 = (size_t)(m0 + ar0) * 1024 + (((ac0 & 3) ^ (ar0 & 3)) * 8);
    size_t b_src0 = (size_t)(wn0 + ar0) * 1024 + (((ac0 & 3) ^ (ar0 & 3)) * 8);

    int a_off[2], b_off[4];
#pragma unroll
    for (int mi = 0; mi < 2; ++mi) {
        int row = wm + mi * 16 + l15;
        a_off[mi] = row * 32 + ((l16 ^ (row & 3)) * 8);
    }
#pragma unroll
    for (int ni = 0; ni < 4; ++ni) {
        int n = wn + ni * 16 + l15;
        b_off[ni] = n * 32 + ((l16 ^ (n & 3)) * 8);
    }

    auto STAGE = [&](int buf, int k0) {
        gld_lds16(Ahi + a_src0 + k0, &Ash[buf][ac0 * 8]);
        gld_lds16(Alo + a_src0 + k0, &Asl[buf][ac0 * 8]);
        gld_lds16(WT3hi + b_src0 + k0, &Bsh[buf][ac0 * 8]);
        gld_lds16(WT3lo + b_src0 + k0, &Bsl[buf][ac0 * 8]);
    };

    v4f acc[2][4] = {};
    STAGE(0, 0);
    __syncthreads();

    for (int kk = 0; kk < 32; ++kk) {
        int cur = kk & 1;
        if (kk < 31) STAGE(cur ^ 1, (kk + 1) * 32);
        v8h ah[2], al[2], bh[4], bl[4];
#pragma unroll
        for (int mi = 0; mi < 2; ++mi) {
            ah[mi] = *(const v8h*)&Ash[cur][a_off[mi]];
            al[mi] = *(const v8h*)&Asl[cur][a_off[mi]];
        }
#pragma unroll
        for (int ni = 0; ni < 4; ++ni) {
            bh[ni] = *(const v8h*)&Bsh[cur][b_off[ni]];
            bl[ni] = *(const v8h*)&Bsl[cur][b_off[ni]];
        }
#pragma unroll
        for (int mi = 0; mi < 2; ++mi)
#pragma unroll
            for (int ni = 0; ni < 4; ++ni) {
                acc[mi][ni] = __builtin_amdgcn_mfma_f32_16x16x32_f16(ah[mi], bh[ni], acc[mi][ni], 0, 0, 0);
                acc[mi][ni] = __builtin_amdgcn_mfma_f32_16x16x32_f16(al[mi], bh[ni], acc[mi][ni], 0, 0, 0);
                acc[mi][ni] = __builtin_amdgcn_mfma_f32_16x16x32_f16(ah[mi], bl[ni], acc[mi][ni], 0, 0, 0);
            }
        __syncthreads();
    }

    if (np >= 16) {
        int n0 = (np - 16) * 128;
#pragma unroll
        for (int mi = 0; mi < 2; ++mi) {
            int row0 = m0 + wm + mi * 16 + l16 * 4;
            int bb = row0 >> 11, ss = row0 & 2047;
#pragma unroll
            for (int ni = 0; ni < 4; ++ni) {
                int col = n0 + wn + ni * 16 + l15;
                int hh = col >> 7, dd = col & 127;
                size_t base = ((size_t)((bb * 8 + hh) * 128 + dd)) * 2048 + ss;
                ushort4 vh, vl;
                float v0 = acc[mi][ni][0] + bv[col];
                float v1 = acc[mi][ni][1] + bv[col];
                float v2 = acc[mi][ni][2] + bv[col];
                float v3 = acc[mi][ni][3] + bv[col];
                splitf16(v0, vh.x, vl.x);
                splitf16(v1, vh.y, vl.y);
                splitf16(v2, vh.z, vl.z);
                splitf16(v3, vh.w, vl.w);
                *(ushort4*)(VThi + base) = vh;
                *(ushort4*)(VTlo + base) = vl;
            }
        }
    } else {
        const float* bias = np < 8 ? bq : bk;
        unsigned short* Dhi = np < 8 ? Qhi : Khi;
        unsigned short* Dlo = np < 8 ? Qlo : Klo;
        float esc = np < 8 ? qscale : 1.f;
        int n0 = (np & 7) * 128;
#pragma unroll
        for (int mi = 0; mi < 2; ++mi) {
#pragma unroll
            for (int r = 0; r < 4; ++r) {
                int row = m0 + wm + mi * 16 + l16 * 4 + r;
#pragma unroll
                for (int ni = 0; ni < 4; ++ni) {
                    int col = n0 + wn + ni * 16 + l15;
                    float v = (acc[mi][ni][r] + bias[col]) * esc;
                    size_t o = (size_t)row * 1024 + col;
                    unsigned short hu, lu;
                    splitf16(v, hu, lu);
                    Dhi[o] = hu; Dlo[o] = lu;
                }
            }
        }
    }
}

// ---------------------------------------------------------------- MFMA attention v4 + T5 setprio + NT OP
__global__ __launch_bounds__(256, 4) void attn_mfma_k(
    const unsigned short* __restrict__ qhi, const unsigned short* __restrict__ qlo,
    const unsigned short* __restrict__ khi, const unsigned short* __restrict__ klo,
    const unsigned short* __restrict__ vthi, const unsigned short* __restrict__ vtlo,
    float* __restrict__ OP, float* __restrict__ ML) {
    __shared__ unsigned short Ks_hi[32 * 128];
    __shared__ unsigned short Ks_lo[32 * 128];
    __shared__ unsigned short Vs_hi[128 * 32];
    __shared__ unsigned short Vs_lo[128 * 32];
    __shared__ unsigned int   Ps[64 * 32];

    int p = blockIdx.x;
    int x = (p >> 3) & 31;
    int g = (p & 7) + ((p >> 8) << 3);
    int bh = g >> 1, z = g & 1;
    int b = bh >> 3, h = bh & 7;
    int q0 = x * 64;
    int tid = threadIdx.x;
    int lane = tid & 63, w = tid >> 6;
    int l15 = lane & 15, l16 = lane >> 4;
    int wm = w * 16;

    v8h qa_h[4], qa_l[4];
    {
        size_t qrow = (size_t)(b * S_LEN + q0 + wm + l15) * H_DIM + h * HDHD;
#pragma unroll
        for (int ks = 0; ks < 4; ++ks) {
            qa_h[ks] = *(const v8h*)(qhi + qrow + ks * 32 + l16 * 8);
            qa_l[ks] = *(const v8h*)(qlo + qrow + ks * 32 + l16 * 8);
        }
    }

    int ktok1 = tid >> 4, kslot1 = tid & 15;
    int ktok2 = ktok1 + 16;
    size_t ksrc1 = (size_t)(b * S_LEN + ktok1) * H_DIM + h * HDHD + ((kslot1 ^ (ktok1 & 7)) * 8);
    size_t ksrc2 = (size_t)(b * S_LEN + ktok2) * H_DIM + h * HDHD + ((kslot1 ^ (ktok2 & 7)) * 8);
    int vd1 = tid >> 2, vslot1 = tid & 3;
    int vd2 = vd1 + 64;
    size_t vsrc1 = (size_t)(bh * HDHD + vd1) * S_LEN + ((vslot1 ^ ((vd1 >> 1) & 3)) * 8);
    size_t vsrc2 = (size_t)(bh * HDHD + vd2) * S_LEN + ((vslot1 ^ ((vd2 >> 1) & 3)) * 8);

    v4f accO[8] = {};
    float mreg[4] = {-1e30f, -1e30f, -1e30f, -1e30f};
    float lreg[4] = {};

    int kt0 = z * 1024;
    for (int it = 0; it < 32; ++it) {
        int kt = kt0 + it * 32;
        __syncthreads();
        size_t koff = (size_t)kt * H_DIM;
        gld_lds16(khi + ksrc1 + koff, &Ks_hi[tid * 8]);
        gld_lds16(khi + ksrc2 + koff, &Ks_hi[(tid + 256) * 8]);
        gld_lds16(klo + ksrc1 + koff, &Ks_lo[tid * 8]);
        gld_lds16(klo + ksrc2 + koff, &Ks_lo[(tid + 256) * 8]);
        gld_lds16(vthi + vsrc1 + kt, &Vs_hi[tid * 8]);
        gld_lds16(vthi + vsrc2 + kt, &Vs_hi[(tid + 256) * 8]);
        gld_lds16(vtlo + vsrc1 + kt, &Vs_lo[tid * 8]);
        gld_lds16(vtlo + vsrc2 + kt, &Vs_lo[(tid + 256) * 8]);
        __syncthreads();

        v4f s0 = {}, s1 = {};
        __builtin_amdgcn_s_setprio(1);
#pragma unroll
        for (int ks = 0; ks < 4; ++ks) {
#pragma unroll
            for (int nt = 0; nt < 2; ++nt) {
                int tok = nt * 16 + l15;
                int slot = (ks * 4 + l16) ^ (tok & 7);
                v8h bhf = *(const v8h*)&Ks_hi[tok * 128 + slot * 8];
                v8h blf = *(const v8h*)&Ks_lo[tok * 128 + slot * 8];
                v4f& ss = nt ? s1 : s0;
                ss = __builtin_amdgcn_mfma_f32_16x16x32_f16(qa_h[ks], bhf, ss, 0, 0, 0);
                ss = __builtin_amdgcn_mfma_f32_16x16x32_f16(qa_l[ks], bhf, ss, 0, 0, 0);
                ss = __builtin_amdgcn_mfma_f32_16x16x32_f16(qa_h[ks], blf, ss, 0, 0, 0);
            }
        }
        __builtin_amdgcn_s_setprio(0);

        float p0[4], p1[4], alpha[4];
#pragma unroll
        for (int r = 0; r < 4; ++r) {
            float tmax = fmaxf(s0[r], s1[r]);
            tmax = fmaxf(tmax, __shfl_xor(tmax, 1));
            tmax = fmaxf(tmax, __shfl_xor(tmax, 2));
            tmax = fmaxf(tmax, __shfl_xor(tmax, 4));
            tmax = fmaxf(tmax, __shfl_xor(tmax, 8));
            float mnew = fmaxf(mreg[r], tmax);
            alpha[r] = __expf(mreg[r] - mnew);
            p0[r] = __expf(s0[r] - mnew);
            p1[r] = __expf(s1[r] - mnew);
            float lt = p0[r] + p1[r];
            lt += __shfl_xor(lt, 1);
            lt += __shfl_xor(lt, 2);
            lt += __shfl_xor(lt, 4);
            lt += __shfl_xor(lt, 8);
            lreg[r] = lreg[r] * alpha[r] + lt;
            mreg[r] = mnew;
        }
#pragma unroll
        for (int nt = 0; nt < 8; ++nt)
#pragma unroll
            for (int r = 0; r < 4; ++r) accO[nt][r] *= alpha[r];

#pragma unroll
        for (int r = 0; r < 4; ++r) {
            int qq = wm + l16 * 4 + r;
            unsigned short ph, pl;
            splitf16(p0[r], ph, pl);
            int k0i = l15;
            Ps[qq * 32 + ((((k0i >> 2) ^ (qq & 7)) << 2) | (k0i & 3))] =
                (unsigned)ph | ((unsigned)pl << 16);
            splitf16(p1[r], ph, pl);
            int k1i = 16 + l15;
            Ps[qq * 32 + ((((k1i >> 2) ^ (qq & 7)) << 2) | (k1i & 3))] =
                (unsigned)ph | ((unsigned)pl << 16);
        }

        int qq = wm + l15;
        int sA = (l16 * 2) ^ (qq & 7);
        int sB = (l16 * 2 + 1) ^ (qq & 7);
        uint4 ua = *(const uint4*)&Ps[qq * 32 + sA * 4];
        uint4 ub = *(const uint4*)&Ps[qq * 32 + sB * 4];
        uint4 ahw, alw;
        ahw.x = (ua.x & 0xffffu) | (ua.y << 16);
        ahw.y = (ua.z & 0xffffu) | (ua.w << 16);
        ahw.z = (ub.x & 0xffffu) | (ub.y << 16);
        ahw.w = (ub.z & 0xffffu) | (ub.w << 16);
        alw.x = (ua.x >> 16) | (ua.y & 0xffff0000u);
        alw.y = (ua.z >> 16) | (ua.w & 0xffff0000u);
        alw.z = (ub.x >> 16) | (ub.y & 0xffff0000u);
        alw.w = (ub.z >> 16) | (ub.w & 0xffff0000u);
        v8h pA_h = __builtin_bit_cast(v8h, ahw);
        v8h pA_l = __builtin_bit_cast(v8h, alw);
        __builtin_amdgcn_s_setprio(1);
#pragma unroll
        for (int nt = 0; nt < 8; ++nt) {
            int d = nt * 16 + l15;
            int slot = l16 ^ ((d >> 1) & 3);
            v8h vhf = *(const v8h*)&Vs_hi[d * 32 + slot * 8];
            v8h vlf = *(const v8h*)&Vs_lo[d * 32 + slot * 8];
            accO[nt] = __builtin_amdgcn_mfma_f32_16x16x32_f16(pA_h, vhf, accO[nt], 0, 0, 0);
            accO[nt] = __builtin_amdgcn_mfma_f32_16x16x32_f16(pA_l, vhf, accO[nt], 0, 0, 0);
            accO[nt] = __builtin_amdgcn_mfma_f32_16x16x32_f16(pA_h, vlf, accO[nt], 0, 0, 0);
        }
        __builtin_amdgcn_s_setprio(0);
    }

#pragma unroll
    for (int r = 0; r < 4; ++r) {
        if (l15 == 0) {
            int q = q0 + wm + l16 * 4 + r;
            size_t mlo = ((size_t)(z * 16 + bh) * 2048 + q) * 2;
            ML[mlo] = mreg[r];
            ML[mlo + 1] = lreg[r];
        }
    }
#pragma unroll
    for (int nt = 0; nt < 8; ++nt) {
#pragma unroll
        for (int r = 0; r < 4; ++r) {
            int q = q0 + wm + l16 * 4 + r;
            size_t o = ((size_t)(z * 16 + bh) * 2048 + q) * 128 + nt * 16 + l15;
            __builtin_nontemporal_store(accO[nt][r], &OP[o]);
        }
    }
}

// ---------------------------------------------------------------- flash combine (NT OP reads)
__global__ __launch_bounds__(256) void attn_combine_k(
    const float* __restrict__ OP, const float* __restrict__ ML,
    unsigned short* __restrict__ ctx_hi, unsigned short* __restrict__ ctx_lo) {
    int tid = threadIdx.x;
    int R = blockIdx.x * 16 + (tid >> 4);
    int bh = R >> 11, q = R & 2047;
    int b = bh >> 3, h = bh & 7;
    int d0 = (tid & 15) * 8;
    size_t ml0 = ((size_t)bh * 2048 + q) * 2;
    size_t ml1 = ((size_t)(16 + bh) * 2048 + q) * 2;
    float m0 = ML[ml0], l0 = ML[ml0 + 1];
    float m1 = ML[ml1], l1 = ML[ml1 + 1];
    float m = fmaxf(m0, m1);
    float w0 = __expf(m0 - m), w1 = __expf(m1 - m);
    float inv = 1.f / (w0 * l0 + w1 * l1);
    const v4f* O0 = (const v4f*)(OP + ((size_t)bh * 2048 + q) * 128 + d0);
    const v4f* O1 = (const v4f*)(OP + ((size_t)(16 + bh) * 2048 + q) * 128 + d0);
    size_t dst = ((size_t)(b * 2048 + q)) * 1024 + h * 128 + d0;
    v4f a0 = __builtin_nontemporal_load(O0);
    v4f a1 = __builtin_nontemporal_load(O0 + 1);
    v4f c0 = __builtin_nontemporal_load(O1);
    v4f c1 = __builtin_nontemporal_load(O1 + 1);
    ushort4 h0, h1, lo0, lo1;
    splitf16((w0 * a0.x + w1 * c0.x) * inv, h0.x, lo0.x);
    splitf16((w0 * a0.y + w1 * c0.y) * inv, h0.y, lo0.y);
    splitf16((w0 * a0.z + w1 * c0.z) * inv, h0.z, lo0.z);
    splitf16((w0 * a0.w + w1 * c0.w) * inv, h0.w, lo0.w);
    splitf16((w0 * a1.x + w1 * c1.x) * inv, h1.x, lo1.x);
    splitf16((w0 * a1.y + w1 * c1.y) * inv, h1.y, lo1.y);
    splitf16((w0 * a1.z + w1 * c1.z) * inv, h1.z, lo1.z);
    splitf16((w0 * a1.w + w1 * c1.w) * inv, h1.w, lo1.w);
    *(ushort4*)(ctx_hi + dst) = h0;
    *(ushort4*)(ctx_hi + dst + 4) = h1;
    *(ushort4*)(ctx_lo + dst) = lo0;
    *(ushort4*)(ctx_lo + dst + 4) = lo1;
}

// ---------------------------------------------------------------- router logits + softmax + top2 scatter
__global__ __launch_bounds__(256) void logits_topk_k(const float* __restrict__ h1,
                                                     const float* __restrict__ Wr2T,
                                                     const float* __restrict__ br2,
                                                     float* __restrict__ out) {
    __shared__ float part[256];
    __shared__ float lg[8][8];
    int tid = threadIdx.x;
    int tok8 = tid >> 5;
    int e = (tid >> 2) & 7;
    int ch = tid & 3;
    int tok = blockIdx.x * 8 + tok8;
    const float4* h4 = (const float4*)(h1 + (size_t)tok * 1024 + ch * 256);
    const float4* w4 = (const float4*)(Wr2T + (size_t)e * 1024 + ch * 256);
    float acc = 0.f;
#pragma unroll
    for (int i = 0; i < 64; ++i) {
        float4 a = h4[i];
        float4 bb = w4[i];
        acc = fmaf(a.x, bb.x, fmaf(a.y, bb.y, fmaf(a.z, bb.z, fmaf(a.w, bb.w, acc))));
    }
    part[tid] = acc;
    __syncthreads();
    if (ch == 0)
        lg[tok8][e] = part[tid] + part[tid + 1] + part[tid + 2] + part[tid + 3] + br2[e];
    __syncthreads();
    if (tid < 8) {
        int myTok = blockIdx.x * 8 + tid;
        float l[8], p[8];
        float mx = -1e30f;
#pragma unroll
        for (int k = 0; k < 8; ++k) { l[k] = lg[tid][k]; mx = fmaxf(mx, l[k]); }
        float sum = 0.f;
#pragma unroll
        for (int k = 0; k < 8; ++k) { p[k] = __expf(l[k] - mx); sum += p[k]; }
        float inv = 1.f / sum;
#pragma unroll
        for (int k = 0; k < 8; ++k) p[k] *= inv;
        const size_t NEC = (size_t)N_TOK * E_EXP * CAPV;
        float* probs_out = out + 2 * NEC;
#pragma unroll
        for (int k = 0; k < 8; ++k) probs_out[(size_t)myTok * 8 + k] = p[k];
        int i1 = 0;
#pragma unroll
        for (int k = 1; k < 8; ++k) if (p[k] > p[i1]) i1 = k;
        int i2 = -1;
#pragma unroll
        for (int k = 0; k < 8; ++k) {
            if (k == i1) continue;
            if (i2 < 0 || p[k] > p[i2]) i2 = k;
        }
        float v1 = p[i1], v2 = p[i2], tv = v1 + v2;
        size_t base = (size_t)myTok * E_EXP * CAPV;
        out[base + (size_t)i1 * CAPV] = 1.f;
        out[base + (size_t)i2 * CAPV] = 1.f;
        out[NEC + base + (size_t)i1 * CAPV] = v1 / tv;
        out[NEC + base + (size_t)i2 * CAPV] = v2 / tv;
    }
}

// ---------------------------------------------------------------- aux loss
__global__ void aux_k(const float* __restrict__ probs, float* __restrict__ out_aux) {
    __shared__ float part[256];
    int tid = threadIdx.x;
    int e = tid & 7, chunk = tid >> 3;
    float s = 0.f;
    for (int t = chunk * 128; t < (chunk + 1) * 128; ++t)
        s += probs[(size_t)t * 8 + e];
    part[tid] = s;
    __syncthreads();
    if (tid < 8) {
        float tot = 0.f;
        for (int c = 0; c < 32; ++c) tot += part[c * 8 + e];
        part[tid] = tot / (float)N_TOK;
    }
    __syncthreads();
    if (tid == 0) {
        float aux = 0.f;
        for (int e2 = 0; e2 < 8; ++e2) {
            float pm = part[e2];
            aux += pm * logf(pm * 8.f + 1e-9f);
        }
        *out_aux = aux;
    }
}

// ---------------------------------------------------------------- launch
extern "C" void kernel_launch(void* const* d_in, const int* in_sizes, int n_in,
                              void* d_out, int out_size, void* d_ws, size_t ws_size,
                              hipStream_t stream) {
    const float* hid = (const float*)d_in[0];
    const float* pos = (const float*)d_in[1];
    const float* We1 = (const float*)d_in[2];
    const float* be1 = (const float*)d_in[3];
    const float* We2 = (const float*)d_in[4];
    const float* be2 = (const float*)d_in[5];
    const float* Ws1 = (const float*)d_in[6];
    const float* bs1 = (const float*)d_in[7];
    const float* Ws2 = (const float*)d_in[8];
    const float* bs2 = (const float*)d_in[9];
    const float* Wq  = (const float*)d_in[10]; const float* bq = (const float*)d_in[11];
    const float* Wk  = (const float*)d_in[12]; const float* bk = (const float*)d_in[13];
    const float* Wv  = (const float*)d_in[14]; const float* bv = (const float*)d_in[15];
    const float* Wo  = (const float*)d_in[16]; const float* bo = (const float*)d_in[17];
    const float* Wr1 = (const float*)d_in[18]; const float* br1 = (const float*)d_in[19];
    const float* Wr2 = (const float*)d_in[20]; const float* br2 = (const float*)d_in[21];

    float* out = (float*)d_out;
    char* base = (char*)d_ws;
    const size_t AC  = (size_t)N_TOK * H_DIM;
    const size_t SPC = AC * 2;
    const size_t FB  = AC * 4;
    const size_t MB  = (size_t)1 << 20;

    unsigned short* B1hi = (unsigned short*)(base);
    unsigned short* B1lo = (unsigned short*)(base + SPC);
    unsigned short* B2hi = (unsigned short*)(base + FB);
    unsigned short* B2lo = (unsigned short*)(base + FB + SPC);
    unsigned short* Qhi  = (unsigned short*)(base + 2 * FB);
    unsigned short* Qlo  = (unsigned short*)(base + 2 * FB + SPC);
    unsigned short* Khi  = (unsigned short*)(base + 3 * FB);
    unsigned short* Klo  = (unsigned short*)(base + 3 * FB + SPC);
    unsigned short* VThi = (unsigned short*)(base + 4 * FB);
    unsigned short* VTlo = (unsigned short*)(base + 4 * FB + SPC);
    float* h1f = (float*)(base + 3 * FB);

    char* wp = base + 5 * FB;
    unsigned short* We1hi = (unsigned short*)(wp);
    unsigned short* We1lo = (unsigned short*)(wp + 2 * MB);
    unsigned short* We2hi = (unsigned short*)(wp + 4 * MB);
    unsigned short* We2lo = (unsigned short*)(wp + 6 * MB);
    unsigned short* QKVhi = (unsigned short*)(wp + 8 * MB);
    unsigned short* QKVlo = (unsigned short*)(wp + 14 * MB);
    unsigned short* Wohi  = (unsigned short*)(wp + 20 * MB);
    unsigned short* Wolo  = (unsigned short*)(wp + 22 * MB);
    unsigned short* Wr1hi = (unsigned short*)(wp + 24 * MB);
    unsigned short* Wr1lo = (unsigned short*)(wp + 26 * MB);
    char* smalls = wp + 28 * MB;
    float* wr2t    = (float*)smalls;
    float* seas24  = wr2t + 8192;
    float* seasons = seas24 + 6144;

    const size_t NEC = (size_t)N_TOK * E_EXP * CAPV;
    const float QSCALE = 0.08838834764831845f;

    float* OP = out;
    float* ML = out + (size_t)2 * 16 * 2048 * 128;

    dim3 blk(256), blk512(512);

    WBatch wb;
    wb.src[0] = We1; wb.dh[0] = We1hi; wb.dl[0] = We1lo;
    wb.src[1] = We2; wb.dh[1] = We2hi; wb.dl[1] = We2lo;
    wb.src[2] = Wq;  wb.dh[2] = QKVhi;                        wb.dl[2] = QKVlo;
    wb.src[3] = Wk;  wb.dh[3] = QKVhi + (size_t)1024 * 1024;  wb.dl[3] = QKVlo + (size_t)1024 * 1024;
    wb.src[4] = Wv;  wb.dh[4] = QKVhi + (size_t)2048 * 1024;  wb.dl[4] = QKVlo + (size_t)2048 * 1024;
    wb.src[5] = Wo;  wb.dh[5] = Wohi;  wb.dl[5] = Wolo;
    wb.src[6] = Wr1; wb.dh[6] = Wr1hi; wb.dl[6] = Wr1lo;

    prep_wconv_k<<<5952, blk, 0, stream>>>(hid, B1hi, B1lo, Ws1, bs1, Ws2, bs2,
                                           seasons, seas24, Wr2, wr2t, wb);

    gemm_split<1, 0, 1, 0><<<256, blk512, 0, stream>>>(B1hi, B1lo, We1hi, We1lo, be1,
        nullptr, B2hi, B2lo,
        We1 + (size_t)1024 * 1024, We1 + (size_t)1025 * 1024, seasons, nullptr, nullptr, 1.f, nullptr);
    gemm_split<2, 0, 1, 0><<<256, blk512, 0, stream>>>(B2hi, B2lo, We2hi, We2lo, be2,
        nullptr, B1hi, B1lo, nullptr, nullptr, nullptr, pos, seas24, 1.f, nullptr);

    gemm_qkv<<<768 + NFILLQ, blk512, 0, stream>>>(B1hi, B1lo, QKVhi, QKVlo, bq, bk, bv,
                                                  Qhi, Qlo, Khi, Klo, VThi, VTlo, QSCALE, out);

    attn_mfma_k<<<1024, blk, 0, stream>>>(Qhi, Qlo, Khi, Klo, VThi, VTlo, OP, ML);
    attn_combine_k<<<2048, blk, 0, stream>>>(OP, ML, B2hi, B2lo);

    gemm_split<0, 0, 1, 32><<<256 + 32, blk512, 0, stream>>>(B2hi, B2lo, Wohi, Wolo, bo,
        nullptr, B1hi, B1lo, nullptr, nullptr, nullptr, nullptr, nullptr, 1.f, out);
    gemm_split<3, 1, 0, 0><<<256, blk512, 0, stream>>>(B1hi, B1lo, Wr1hi, Wr1lo, br1,
        h1f, nullptr, nullptr, nullptr, nullptr, nullptr, nullptr, nullptr, 1.f, nullptr);

    logits_topk_k<<<512, blk, 0, stream>>>(h1f, wr2t, br2, out);
    aux_k<<<1, blk, 0, stream>>>(out + 2 * NEC, out + 2 * NEC + (size_t)N_TOK * E_EXP);
}

// Round 20
// 512.364 us; speedup vs baseline: 1.0093x; 1.0093x over previous
//
#include <hip/hip_runtime.h>
#include <hip/hip_fp16.h>
#include <math.h>

#define N_TOK 4096
#define S_LEN 2048
#define H_DIM 1024
#define E_EXP 8
#define CAPV  1536
#define NHEAD 8
#define HDHD  128

#define SCRATCH_F4 2129920u
#define TOTAL_F4   25165824u

typedef __attribute__((ext_vector_type(8))) _Float16 v8h;
typedef __attribute__((ext_vector_type(4))) float v4f;

__device__ __forceinline__ void splitf16(float v, unsigned short& h, unsigned short& l) {
    __half hh = __float2half(v);
    h = __half_as_ushort(hh);
    l = __half_as_ushort(__float2half(v - __half2float(hh)));
}

__device__ __forceinline__ void gld_lds16(const void* g, void* l) {
    __builtin_amdgcn_global_load_lds(
        (const __attribute__((address_space(1))) unsigned int*)g,
        (__attribute__((address_space(3))) unsigned int*)l,
        16, 0, 0);
}

struct WBatch {
    const float* src[7];
    unsigned short* dh[7];
    unsigned short* dl[7];
};

// ---------------------------------------------------------------- merged prep + weight conversion
__global__ __launch_bounds__(256) void prep_wconv_k(
    const float* __restrict__ hid, unsigned short* __restrict__ hi,
    unsigned short* __restrict__ lo,
    const float* __restrict__ Ws1, const float* __restrict__ bs1,
    const float* __restrict__ Ws2, const float* __restrict__ bs2,
    float* __restrict__ seasons, float* __restrict__ seas24,
    const float* __restrict__ Wr2, float* __restrict__ wr2t, WBatch wb) {
    __shared__ unsigned short Hs[64][65];
    __shared__ unsigned short Ls[64][65];
    int blk = blockIdx.x;
    int tid = threadIdx.x;
    if (blk < 4096) {
        int i = blk * 256 + tid;
        float4 v = ((const float4*)hid)[i];
        ushort4 h, l;
        splitf16(v.x, h.x, l.x);
        splitf16(v.y, h.y, l.y);
        splitf16(v.z, h.z, l.z);
        splitf16(v.w, h.w, l.w);
        ((ushort4*)hi)[i] = h;
        ((ushort4*)lo)[i] = l;
    } else if (blk < 4104) {
        int s = (blk - 4096) * 256 + tid;
        if (s < S_LEN) {
            double a = (double)s * 2.0 * M_PI / 24.0;
            seasons[s] = (float)sin(a);
        }
    } else if (blk < 4128) {
        float* hbuf = (float*)Hs;
        int m = blk - 4104;
        double a = (double)m * 2.0 * M_PI / 24.0;
        float sv = (float)sin(a);
        int j = tid;
        hbuf[j] = fmaxf(sv * Ws1[j] + bs1[j], 0.f);
        __syncthreads();
        float acc = bs2[j];
        for (int i = 0; i < 256; ++i) acc = fmaf(hbuf[i], Ws2[i * 256 + j], acc);
        seas24[m * 256 + j] = acc;
    } else if (blk < 4160) {
        int i = (blk - 4128) * 256 + tid;
        int k = i >> 3, e = i & 7;
        wr2t[e * 1024 + k] = Wr2[i];
    } else {
        int i2 = blk - 4160;
        int wi = i2 >> 8;
        int rem = i2 & 255;
        int k0 = (rem >> 4) << 6, n0 = (rem & 15) << 6;
        const float* __restrict__ W = wb.src[wi];
        unsigned short* __restrict__ Thi = wb.dh[wi];
        unsigned short* __restrict__ Tlo = wb.dl[wi];
#pragma unroll
        for (int i = 0; i < 4; ++i) {
            int idx = tid + i * 256;
            int kk = idx >> 4, n4 = idx & 15;
            float4 v = *(const float4*)(W + (size_t)(k0 + kk) * 1024 + n0 + n4 * 4);
            unsigned short h, l;
            splitf16(v.x, h, l); Hs[n4 * 4 + 0][kk] = h; Ls[n4 * 4 + 0][kk] = l;
            splitf16(v.y, h, l); Hs[n4 * 4 + 1][kk] = h; Ls[n4 * 4 + 1][kk] = l;
            splitf16(v.z, h, l); Hs[n4 * 4 + 2][kk] = h; Ls[n4 * 4 + 2][kk] = l;
            splitf16(v.w, h, l); Hs[n4 * 4 + 3][kk] = h; Ls[n4 * 4 + 3][kk] = l;
        }
        __syncthreads();
#pragma unroll
        for (int i = 0; i < 4; ++i) {
            int idx = tid + i * 256;
            int n = idx >> 4, k4 = idx & 15;
            ushort4 h = make_ushort4(Hs[n][k4 * 4], Hs[n][k4 * 4 + 1], Hs[n][k4 * 4 + 2], Hs[n][k4 * 4 + 3]);
            ushort4 l = make_ushort4(Ls[n][k4 * 4], Ls[n][k4 * 4 + 1], Ls[n][k4 * 4 + 2], Ls[n][k4 * 4 + 3]);
            *(ushort4*)(Thi + (size_t)(n0 + n) * 1024 + k0 + k4 * 4) = h;
            *(ushort4*)(Tlo + (size_t)(n0 + n) * 1024 + k0 + k4 * 4) = l;
        }
    }
}

// ---------------------------------------------------------------- co-scheduled fill body
__device__ __forceinline__ void fill_body(float* __restrict__ p, size_t f40, size_t f41, int nblk) {
    v4f z = {0.f, 0.f, 0.f, 0.f};
    v4f* o = (v4f*)p;
    size_t n = f41 - f40;
    size_t T = blockDim.x;
    for (size_t i = (size_t)blockIdx.x * T + threadIdx.x; i < n; i += (size_t)nblk * T)
        __builtin_nontemporal_store(z, o + f40 + i);
}

// ---------------------------------------------------------------- split-f16 MFMA GEMM
// 128x128 tile, 512 threads = 8 waves (4M x 2N), 32x64/wave, BK=32, dbuf, XCD swizzle.
template <int MODE, int EMITF, int EMITS, int FILLN>
__global__ __launch_bounds__(512, 4) void gemm_split(
    const unsigned short* __restrict__ Ahi, const unsigned short* __restrict__ Alo,
    const unsigned short* __restrict__ WThi, const unsigned short* __restrict__ WTlo,
    const float* __restrict__ bias, float* __restrict__ Cf,
    unsigned short* __restrict__ Chi, unsigned short* __restrict__ Clo,
    const float* __restrict__ rowT, const float* __restrict__ rowS,
    const float* __restrict__ seasons, const float* __restrict__ pos,
    const float* __restrict__ seas24, float escale, float* __restrict__ fillp) {
    if (FILLN > 0) {
        if (blockIdx.x < (unsigned)FILLN) {
            fill_body(fillp, 0, SCRATCH_F4, FILLN);
            return;
        }
    }
    __shared__ unsigned short Ash[2][128 * 32];
    __shared__ unsigned short Asl[2][128 * 32];
    __shared__ unsigned short Bsh[2][128 * 32];
    __shared__ unsigned short Bsl[2][128 * 32];
    int tid = threadIdx.x;
    int lane = tid & 63, w = tid >> 6;
    int l15 = lane & 15, l16 = lane >> 4;
    int wm = (w >> 1) * 32, wn = (w & 1) * 64;

    int bid = blockIdx.x - FILLN;
    int mp = (bid & 7) + ((bid >> 6) << 3);
    int np = (bid >> 3) & 7;
    int m0 = mp * 128, n0 = np * 128;

    int ac0 = tid;
    int ar0 = ac0 >> 2;
    size_t a_src0 = (size_t)(m0 + ar0) * 1024 + (((ac0 & 3) ^ (ar0 & 3)) * 8);
    size_t b_src0 = (size_t)(n0 + ar0) * 1024 + (((ac0 & 3) ^ (ar0 & 3)) * 8);

    int a_off[2], b_off[4];
#pragma unroll
    for (int mi = 0; mi < 2; ++mi) {
        int row = wm + mi * 16 + l15;
        a_off[mi] = row * 32 + ((l16 ^ (row & 3)) * 8);
    }
#pragma unroll
    for (int ni = 0; ni < 4; ++ni) {
        int n = wn + ni * 16 + l15;
        b_off[ni] = n * 32 + ((l16 ^ (n & 3)) * 8);
    }

    auto STAGE = [&](int buf, int k0) {
        gld_lds16(Ahi + a_src0 + k0, &Ash[buf][ac0 * 8]);
        gld_lds16(Alo + a_src0 + k0, &Asl[buf][ac0 * 8]);
        gld_lds16(WThi + b_src0 + k0, &Bsh[buf][ac0 * 8]);
        gld_lds16(WTlo + b_src0 + k0, &Bsl[buf][ac0 * 8]);
    };

    v4f acc[2][4] = {};
    STAGE(0, 0);
    __syncthreads();

    for (int kk = 0; kk < 32; ++kk) {
        int cur = kk & 1;
        if (kk < 31) STAGE(cur ^ 1, (kk + 1) * 32);
        v8h ah[2], al[2], bh[4], bl[4];
#pragma unroll
        for (int mi = 0; mi < 2; ++mi) {
            ah[mi] = *(const v8h*)&Ash[cur][a_off[mi]];
            al[mi] = *(const v8h*)&Asl[cur][a_off[mi]];
        }
#pragma unroll
        for (int ni = 0; ni < 4; ++ni) {
            bh[ni] = *(const v8h*)&Bsh[cur][b_off[ni]];
            bl[ni] = *(const v8h*)&Bsl[cur][b_off[ni]];
        }
#pragma unroll
        for (int mi = 0; mi < 2; ++mi)
#pragma unroll
            for (int ni = 0; ni < 4; ++ni) {
                acc[mi][ni] = __builtin_amdgcn_mfma_f32_16x16x32_f16(ah[mi], bh[ni], acc[mi][ni], 0, 0, 0);
                acc[mi][ni] = __builtin_amdgcn_mfma_f32_16x16x32_f16(al[mi], bh[ni], acc[mi][ni], 0, 0, 0);
                acc[mi][ni] = __builtin_amdgcn_mfma_f32_16x16x32_f16(ah[mi], bl[ni], acc[mi][ni], 0, 0, 0);
            }
        __syncthreads();
    }

#pragma unroll
    for (int mi = 0; mi < 2; ++mi) {
#pragma unroll
        for (int r = 0; r < 4; ++r) {
            int row = m0 + wm + mi * 16 + l16 * 4 + r;
            int s = row & (S_LEN - 1);
            float tval = 0.f, seval = 0.f;
            if (MODE == 1) { tval = (float)s; seval = seasons[s]; }
#pragma unroll
            for (int ni = 0; ni < 4; ++ni) {
                int col = n0 + wn + ni * 16 + l15;
                float v = acc[mi][ni][r] + bias[col];
                if (MODE == 1) v += tval * rowT[col] + seval * rowS[col];
                if (MODE == 2) v += pos[(size_t)s * 1024 + col] + seas24[(s % 24) * 256 + (col & 255)];
                if (MODE == 1 || MODE == 3) v = fmaxf(v, 0.f);
                size_t o = (size_t)row * 1024 + col;
                if (EMITF) Cf[o] = v;
                if (EMITS) {
                    unsigned short hu, lu;
                    splitf16(v * escale, hu, lu);
                    Chi[o] = hu; Clo[o] = lu;
                }
            }
        }
    }
}

// ---------------------------------------------------------------- fused QKV GEMM + co-scheduled big fill
#define NFILLQ 128
__global__ __launch_bounds__(512, 4) void gemm_qkv(
    const unsigned short* __restrict__ Ahi, const unsigned short* __restrict__ Alo,
    const unsigned short* __restrict__ WT3hi, const unsigned short* __restrict__ WT3lo,
    const float* __restrict__ bq, const float* __restrict__ bk,
    const float* __restrict__ bv,
    unsigned short* __restrict__ Qhi, unsigned short* __restrict__ Qlo,
    unsigned short* __restrict__ Khi, unsigned short* __restrict__ Klo,
    unsigned short* __restrict__ VThi, unsigned short* __restrict__ VTlo,
    float qscale, float* __restrict__ fillp) {
    if (blockIdx.x < NFILLQ) {
        fill_body(fillp, SCRATCH_F4, TOTAL_F4, NFILLQ);
        return;
    }
    __shared__ unsigned short Ash[2][128 * 32];
    __shared__ unsigned short Asl[2][128 * 32];
    __shared__ unsigned short Bsh[2][128 * 32];
    __shared__ unsigned short Bsl[2][128 * 32];
    int tid = threadIdx.x;
    int lane = tid & 63, w = tid >> 6;
    int l15 = lane & 15, l16 = lane >> 4;
    int wm = (w >> 1) * 32, wn = (w & 1) * 64;

    int bid = blockIdx.x - NFILLQ;
    int t = bid >> 3;
    int np = t % 24;
    int mp = (bid & 7) + (t / 24) * 8;
    int m0 = mp * 128;
    int wn0 = np * 128;

    int ac0 = tid;
    int ar0 = ac0 >> 2;
    size_t a_src0 = (size_t)(m0 + ar0) * 1024 + (((ac0 & 3) ^ (ar0 & 3)) * 8);
    size_t b_src0 = (size_t)(wn0 + ar0) * 1024 + (((ac0 & 3) ^ (ar0 & 3)) * 8);

    int a_off[2], b_off[4];
#pragma unroll
    for (int mi = 0; mi < 2; ++mi) {
        int row = wm + mi * 16 + l15;
        a_off[mi] = row * 32 + ((l16 ^ (row & 3)) * 8);
    }
#pragma unroll
    for (int ni = 0; ni < 4; ++ni) {
        int n = wn + ni * 16 + l15;
        b_off[ni] = n * 32 + ((l16 ^ (n & 3)) * 8);
    }

    auto STAGE = [&](int buf, int k0) {
        gld_lds16(Ahi + a_src0 + k0, &Ash[buf][ac0 * 8]);
        gld_lds16(Alo + a_src0 + k0, &Asl[buf][ac0 * 8]);
        gld_lds16(WT3hi + b_src0 + k0, &Bsh[buf][ac0 * 8]);
        gld_lds16(WT3lo + b_src0 + k0, &Bsl[buf][ac0 * 8]);
    };

    v4f acc[2][4] = {};
    STAGE(0, 0);
    __syncthreads();

    for (int kk = 0; kk < 32; ++kk) {
        int cur = kk & 1;
        if (kk < 31) STAGE(cur ^ 1, (kk + 1) * 32);
        v8h ah[2], al[2], bh[4], bl[4];
#pragma unroll
        for (int mi = 0; mi < 2; ++mi) {
            ah[mi] = *(const v8h*)&Ash[cur][a_off[mi]];
            al[mi] = *(const v8h*)&Asl[cur][a_off[mi]];
        }
#pragma unroll
        for (int ni = 0; ni < 4; ++ni) {
            bh[ni] = *(const v8h*)&Bsh[cur][b_off[ni]];
            bl[ni] = *(const v8h*)&Bsl[cur][b_off[ni]];
        }
#pragma unroll
        for (int mi = 0; mi < 2; ++mi)
#pragma unroll
            for (int ni = 0; ni < 4; ++ni) {
                acc[mi][ni] = __builtin_amdgcn_mfma_f32_16x16x32_f16(ah[mi], bh[ni], acc[mi][ni], 0, 0, 0);
                acc[mi][ni] = __builtin_amdgcn_mfma_f32_16x16x32_f16(al[mi], bh[ni], acc[mi][ni], 0, 0, 0);
                acc[mi][ni] = __builtin_amdgcn_mfma_f32_16x16x32_f16(ah[mi], bl[ni], acc[mi][ni], 0, 0, 0);
            }
        __syncthreads();
    }

    if (np >= 16) {
        int n0 = (np - 16) * 128;
#pragma unroll
        for (int mi = 0; mi < 2; ++mi) {
            int row0 = m0 + wm + mi * 16 + l16 * 4;
            int bb = row0 >> 11, ss = row0 & 2047;
#pragma unroll
            for (int ni = 0; ni < 4; ++ni) {
                int col = n0 + wn + ni * 16 + l15;
                int hh = col >> 7, dd = col & 127;
                size_t base = ((size_t)((bb * 8 + hh) * 128 + dd)) * 2048 + ss;
                ushort4 vh, vl;
                float v0 = acc[mi][ni][0] + bv[col];
                float v1 = acc[mi][ni][1] + bv[col];
                float v2 = acc[mi][ni][2] + bv[col];
                float v3 = acc[mi][ni][3] + bv[col];
                splitf16(v0, vh.x, vl.x);
                splitf16(v1, vh.y, vl.y);
                splitf16(v2, vh.z, vl.z);
                splitf16(v3, vh.w, vl.w);
                *(ushort4*)(VThi + base) = vh;
                *(ushort4*)(VTlo + base) = vl;
            }
        }
    } else {
        const float* bias = np < 8 ? bq : bk;
        unsigned short* Dhi = np < 8 ? Qhi : Khi;
        unsigned short* Dlo = np < 8 ? Qlo : Klo;
        float esc = np < 8 ? qscale : 1.f;
        int n0 = (np & 7) * 128;
#pragma unroll
        for (int mi = 0; mi < 2; ++mi) {
#pragma unroll
            for (int r = 0; r < 4; ++r) {
                int row = m0 + wm + mi * 16 + l16 * 4 + r;
#pragma unroll
                for (int ni = 0; ni < 4; ++ni) {
                    int col = n0 + wn + ni * 16 + l15;
                    float v = (acc[mi][ni][r] + bias[col]) * esc;
                    size_t o = (size_t)row * 1024 + col;
                    unsigned short hu, lu;
                    splitf16(v, hu, lu);
                    Dhi[o] = hu; Dlo[o] = lu;
                }
            }
        }
    }
}

// ---------------------------------------------------------------- MFMA attention v4 + T5 setprio
__global__ __launch_bounds__(256, 4) void attn_mfma_k(
    const unsigned short* __restrict__ qhi, const unsigned short* __restrict__ qlo,
    const unsigned short* __restrict__ khi, const unsigned short* __restrict__ klo,
    const unsigned short* __restrict__ vthi, const unsigned short* __restrict__ vtlo,
    float* __restrict__ OP, float* __restrict__ ML) {
    __shared__ unsigned short Ks_hi[32 * 128];
    __shared__ unsigned short Ks_lo[32 * 128];
    __shared__ unsigned short Vs_hi[128 * 32];
    __shared__ unsigned short Vs_lo[128 * 32];
    __shared__ unsigned int   Ps[64 * 32];

    int p = blockIdx.x;
    int x = (p >> 3) & 31;
    int g = (p & 7) + ((p >> 8) << 3);
    int bh = g >> 1, z = g & 1;
    int b = bh >> 3, h = bh & 7;
    int q0 = x * 64;
    int tid = threadIdx.x;
    int lane = tid & 63, w = tid >> 6;
    int l15 = lane & 15, l16 = lane >> 4;
    int wm = w * 16;

    v8h qa_h[4], qa_l[4];
    {
        size_t qrow = (size_t)(b * S_LEN + q0 + wm + l15) * H_DIM + h * HDHD;
#pragma unroll
        for (int ks = 0; ks < 4; ++ks) {
            qa_h[ks] = *(const v8h*)(qhi + qrow + ks * 32 + l16 * 8);
            qa_l[ks] = *(const v8h*)(qlo + qrow + ks * 32 + l16 * 8);
        }
    }

    int ktok1 = tid >> 4, kslot1 = tid & 15;
    int ktok2 = ktok1 + 16;
    size_t ksrc1 = (size_t)(b * S_LEN + ktok1) * H_DIM + h * HDHD + ((kslot1 ^ (ktok1 & 7)) * 8);
    size_t ksrc2 = (size_t)(b * S_LEN + ktok2) * H_DIM + h * HDHD + ((kslot1 ^ (ktok2 & 7)) * 8);
    int vd1 = tid >> 2, vslot1 = tid & 3;
    int vd2 = vd1 + 64;
    size_t vsrc1 = (size_t)(bh * HDHD + vd1) * S_LEN + ((vslot1 ^ ((vd1 >> 1) & 3)) * 8);
    size_t vsrc2 = (size_t)(bh * HDHD + vd2) * S_LEN + ((vslot1 ^ ((vd2 >> 1) & 3)) * 8);

    v4f accO[8] = {};
    float mreg[4] = {-1e30f, -1e30f, -1e30f, -1e30f};
    float lreg[4] = {};

    int kt0 = z * 1024;
    for (int it = 0; it < 32; ++it) {
        int kt = kt0 + it * 32;
        __syncthreads();
        size_t koff = (size_t)kt * H_DIM;
        gld_lds16(khi + ksrc1 + koff, &Ks_hi[tid * 8]);
        gld_lds16(khi + ksrc2 + koff, &Ks_hi[(tid + 256) * 8]);
        gld_lds16(klo + ksrc1 + koff, &Ks_lo[tid * 8]);
        gld_lds16(klo + ksrc2 + koff, &Ks_lo[(tid + 256) * 8]);
        gld_lds16(vthi + vsrc1 + kt, &Vs_hi[tid * 8]);
        gld_lds16(vthi + vsrc2 + kt, &Vs_hi[(tid + 256) * 8]);
        gld_lds16(vtlo + vsrc1 + kt, &Vs_lo[tid * 8]);
        gld_lds16(vtlo + vsrc2 + kt, &Vs_lo[(tid + 256) * 8]);
        __syncthreads();

        v4f s0 = {}, s1 = {};
        __builtin_amdgcn_s_setprio(1);
#pragma unroll
        for (int ks = 0; ks < 4; ++ks) {
#pragma unroll
            for (int nt = 0; nt < 2; ++nt) {
                int tok = nt * 16 + l15;
                int slot = (ks * 4 + l16) ^ (tok & 7);
                v8h bhf = *(const v8h*)&Ks_hi[tok * 128 + slot * 8];
                v8h blf = *(const v8h*)&Ks_lo[tok * 128 + slot * 8];
                v4f& ss = nt ? s1 : s0;
                ss = __builtin_amdgcn_mfma_f32_16x16x32_f16(qa_h[ks], bhf, ss, 0, 0, 0);
                ss = __builtin_amdgcn_mfma_f32_16x16x32_f16(qa_l[ks], bhf, ss, 0, 0, 0);
                ss = __builtin_amdgcn_mfma_f32_16x16x32_f16(qa_h[ks], blf, ss, 0, 0, 0);
            }
        }
        __builtin_amdgcn_s_setprio(0);

        float p0[4], p1[4], alpha[4];
#pragma unroll
        for (int r = 0; r < 4; ++r) {
            float tmax = fmaxf(s0[r], s1[r]);
            tmax = fmaxf(tmax, __shfl_xor(tmax, 1));
            tmax = fmaxf(tmax, __shfl_xor(tmax, 2));
            tmax = fmaxf(tmax, __shfl_xor(tmax, 4));
            tmax = fmaxf(tmax, __shfl_xor(tmax, 8));
            float mnew = fmaxf(mreg[r], tmax);
            alpha[r] = __expf(mreg[r] - mnew);
            p0[r] = __expf(s0[r] - mnew);
            p1[r] = __expf(s1[r] - mnew);
            float lt = p0[r] + p1[r];
            lt += __shfl_xor(lt, 1);
            lt += __shfl_xor(lt, 2);
            lt += __shfl_xor(lt, 4);
            lt += __shfl_xor(lt, 8);
            lreg[r] = lreg[r] * alpha[r] + lt;
            mreg[r] = mnew;
        }
#pragma unroll
        for (int nt = 0; nt < 8; ++nt)
#pragma unroll
            for (int r = 0; r < 4; ++r) accO[nt][r] *= alpha[r];

#pragma unroll
        for (int r = 0; r < 4; ++r) {
            int qq = wm + l16 * 4 + r;
            unsigned short ph, pl;
            splitf16(p0[r], ph, pl);
            int k0i = l15;
            Ps[qq * 32 + ((((k0i >> 2) ^ (qq & 7)) << 2) | (k0i & 3))] =
                (unsigned)ph | ((unsigned)pl << 16);
            splitf16(p1[r], ph, pl);
            int k1i = 16 + l15;
            Ps[qq * 32 + ((((k1i >> 2) ^ (qq & 7)) << 2) | (k1i & 3))] =
                (unsigned)ph | ((unsigned)pl << 16);
        }

        int qq = wm + l15;
        int sA = (l16 * 2) ^ (qq & 7);
        int sB = (l16 * 2 + 1) ^ (qq & 7);
        uint4 ua = *(const uint4*)&Ps[qq * 32 + sA * 4];
        uint4 ub = *(const uint4*)&Ps[qq * 32 + sB * 4];
        uint4 ahw, alw;
        ahw.x = (ua.x & 0xffffu) | (ua.y << 16);
        ahw.y = (ua.z & 0xffffu) | (ua.w << 16);
        ahw.z = (ub.x & 0xffffu) | (ub.y << 16);
        ahw.w = (ub.z & 0xffffu) | (ub.w << 16);
        alw.x = (ua.x >> 16) | (ua.y & 0xffff0000u);
        alw.y = (ua.z >> 16) | (ua.w & 0xffff0000u);
        alw.z = (ub.x >> 16) | (ub.y & 0xffff0000u);
        alw.w = (ub.z >> 16) | (ub.w & 0xffff0000u);
        v8h pA_h = __builtin_bit_cast(v8h, ahw);
        v8h pA_l = __builtin_bit_cast(v8h, alw);
        __builtin_amdgcn_s_setprio(1);
#pragma unroll
        for (int nt = 0; nt < 8; ++nt) {
            int d = nt * 16 + l15;
            int slot = l16 ^ ((d >> 1) & 3);
            v8h vhf = *(const v8h*)&Vs_hi[d * 32 + slot * 8];
            v8h vlf = *(const v8h*)&Vs_lo[d * 32 + slot * 8];
            accO[nt] = __builtin_amdgcn_mfma_f32_16x16x32_f16(pA_h, vhf, accO[nt], 0, 0, 0);
            accO[nt] = __builtin_amdgcn_mfma_f32_16x16x32_f16(pA_l, vhf, accO[nt], 0, 0, 0);
            accO[nt] = __builtin_amdgcn_mfma_f32_16x16x32_f16(pA_h, vlf, accO[nt], 0, 0, 0);
        }
        __builtin_amdgcn_s_setprio(0);
    }

#pragma unroll
    for (int r = 0; r < 4; ++r) {
        if (l15 == 0) {
            int q = q0 + wm + l16 * 4 + r;
            size_t mlo = ((size_t)(z * 16 + bh) * 2048 + q) * 2;
            ML[mlo] = mreg[r];
            ML[mlo + 1] = lreg[r];
        }
    }
#pragma unroll
    for (int nt = 0; nt < 8; ++nt) {
#pragma unroll
        for (int r = 0; r < 4; ++r) {
            int q = q0 + wm + l16 * 4 + r;
            size_t o = ((size_t)(z * 16 + bh) * 2048 + q) * 128 + nt * 16 + l15;
            OP[o] = accO[nt][r];
        }
    }
}

// ---------------------------------------------------------------- flash combine
__global__ __launch_bounds__(256) void attn_combine_k(
    const float* __restrict__ OP, const float* __restrict__ ML,
    unsigned short* __restrict__ ctx_hi, unsigned short* __restrict__ ctx_lo) {
    int tid = threadIdx.x;
    int R = blockIdx.x * 16 + (tid >> 4);
    int bh = R >> 11, q = R & 2047;
    int b = bh >> 3, h = bh & 7;
    int d0 = (tid & 15) * 8;
    size_t ml0 = ((size_t)bh * 2048 + q) * 2;
    size_t ml1 = ((size_t)(16 + bh) * 2048 + q) * 2;
    float m0 = ML[ml0], l0 = ML[ml0 + 1];
    float m1 = ML[ml1], l1 = ML[ml1 + 1];
    float m = fmaxf(m0, m1);
    float w0 = __expf(m0 - m), w1 = __expf(m1 - m);
    float inv = 1.f / (w0 * l0 + w1 * l1);
    const float* O0 = OP + ((size_t)bh * 2048 + q) * 128 + d0;
    const float* O1 = OP + ((size_t)(16 + bh) * 2048 + q) * 128 + d0;
    size_t dst = ((size_t)(b * 2048 + q)) * 1024 + h * 128 + d0;
    float4 a0 = *(const float4*)O0;
    float4 a1 = *(const float4*)(O0 + 4);
    float4 c0 = *(const float4*)O1;
    float4 c1 = *(const float4*)(O1 + 4);
    ushort4 h0, h1, lo0, lo1;
    splitf16((w0 * a0.x + w1 * c0.x) * inv, h0.x, lo0.x);
    splitf16((w0 * a0.y + w1 * c0.y) * inv, h0.y, lo0.y);
    splitf16((w0 * a0.z + w1 * c0.z) * inv, h0.z, lo0.z);
    splitf16((w0 * a0.w + w1 * c0.w) * inv, h0.w, lo0.w);
    splitf16((w0 * a1.x + w1 * c1.x) * inv, h1.x, lo1.x);
    splitf16((w0 * a1.y + w1 * c1.y) * inv, h1.y, lo1.y);
    splitf16((w0 * a1.z + w1 * c1.z) * inv, h1.z, lo1.z);
    splitf16((w0 * a1.w + w1 * c1.w) * inv, h1.w, lo1.w);
    *(ushort4*)(ctx_hi + dst) = h0;
    *(ushort4*)(ctx_hi + dst + 4) = h1;
    *(ushort4*)(ctx_lo + dst) = lo0;
    *(ushort4*)(ctx_lo + dst + 4) = lo1;
}

// ---------------------------------------------------------------- router logits + softmax + top2 scatter
__global__ __launch_bounds__(256) void logits_topk_k(const float* __restrict__ h1,
                                                     const float* __restrict__ Wr2T,
                                                     const float* __restrict__ br2,
                                                     float* __restrict__ out) {
    __shared__ float part[256];
    __shared__ float lg[8][8];
    int tid = threadIdx.x;
    int tok8 = tid >> 5;
    int e = (tid >> 2) & 7;
    int ch = tid & 3;
    int tok = blockIdx.x * 8 + tok8;
    const float4* h4 = (const float4*)(h1 + (size_t)tok * 1024 + ch * 256);
    const float4* w4 = (const float4*)(Wr2T + (size_t)e * 1024 + ch * 256);
    float acc = 0.f;
#pragma unroll
    for (int i = 0; i < 64; ++i) {
        float4 a = h4[i];
        float4 bb = w4[i];
        acc = fmaf(a.x, bb.x, fmaf(a.y, bb.y, fmaf(a.z, bb.z, fmaf(a.w, bb.w, acc))));
    }
    part[tid] = acc;
    __syncthreads();
    if (ch == 0)
        lg[tok8][e] = part[tid] + part[tid + 1] + part[tid + 2] + part[tid + 3] + br2[e];
    __syncthreads();
    if (tid < 8) {
        int myTok = blockIdx.x * 8 + tid;
        float l[8], p[8];
        float mx = -1e30f;
#pragma unroll
        for (int k = 0; k < 8; ++k) { l[k] = lg[tid][k]; mx = fmaxf(mx, l[k]); }
        float sum = 0.f;
#pragma unroll
        for (int k = 0; k < 8; ++k) { p[k] = __expf(l[k] - mx); sum += p[k]; }
        float inv = 1.f / sum;
#pragma unroll
        for (int k = 0; k < 8; ++k) p[k] *= inv;
        const size_t NEC = (size_t)N_TOK * E_EXP * CAPV;
        float* probs_out = out + 2 * NEC;
#pragma unroll
        for (int k = 0; k < 8; ++k) probs_out[(size_t)myTok * 8 + k] = p[k];
        int i1 = 0;
#pragma unroll
        for (int k = 1; k < 8; ++k) if (p[k] > p[i1]) i1 = k;
        int i2 = -1;
#pragma unroll
        for (int k = 0; k < 8; ++k) {
            if (k == i1) continue;
            if (i2 < 0 || p[k] > p[i2]) i2 = k;
        }
        float v1 = p[i1], v2 = p[i2], tv = v1 + v2;
        size_t base = (size_t)myTok * E_EXP * CAPV;
        out[base + (size_t)i1 * CAPV] = 1.f;
        out[base + (size_t)i2 * CAPV] = 1.f;
        out[NEC + base + (size_t)i1 * CAPV] = v1 / tv;
        out[NEC + base + (size_t)i2 * CAPV] = v2 / tv;
    }
}

// ---------------------------------------------------------------- aux loss
__global__ void aux_k(const float* __restrict__ probs, float* __restrict__ out_aux) {
    __shared__ float part[256];
    int tid = threadIdx.x;
    int e = tid & 7, chunk = tid >> 3;
    float s = 0.f;
    for (int t = chunk * 128; t < (chunk + 1) * 128; ++t)
        s += probs[(size_t)t * 8 + e];
    part[tid] = s;
    __syncthreads();
    if (tid < 8) {
        float tot = 0.f;
        for (int c = 0; c < 32; ++c) tot += part[c * 8 + e];
        part[tid] = tot / (float)N_TOK;
    }
    __syncthreads();
    if (tid == 0) {
        float aux = 0.f;
        for (int e2 = 0; e2 < 8; ++e2) {
            float pm = part[e2];
            aux += pm * logf(pm * 8.f + 1e-9f);
        }
        *out_aux = aux;
    }
}

// ---------------------------------------------------------------- launch
extern "C" void kernel_launch(void* const* d_in, const int* in_sizes, int n_in,
                              void* d_out, int out_size, void* d_ws, size_t ws_size,
                              hipStream_t stream) {
    const float* hid = (const float*)d_in[0];
    const float* pos = (const float*)d_in[1];
    const float* We1 = (const float*)d_in[2];
    const float* be1 = (const float*)d_in[3];
    const float* We2 = (const float*)d_in[4];
    const float* be2 = (const float*)d_in[5];
    const float* Ws1 = (const float*)d_in[6];
    const float* bs1 = (const float*)d_in[7];
    const float* Ws2 = (const float*)d_in[8];
    const float* bs2 = (const float*)d_in[9];
    const float* Wq  = (const float*)d_in[10]; const float* bq = (const float*)d_in[11];
    const float* Wk  = (const float*)d_in[12]; const float* bk = (const float*)d_in[13];
    const float* Wv  = (const float*)d_in[14]; const float* bv = (const float*)d_in[15];
    const float* Wo  = (const float*)d_in[16]; const float* bo = (const float*)d_in[17];
    const float* Wr1 = (const float*)d_in[18]; const float* br1 = (const float*)d_in[19];
    const float* Wr2 = (const float*)d_in[20]; const float* br2 = (const float*)d_in[21];

    float* out = (float*)d_out;
    char* base = (char*)d_ws;
    const size_t AC  = (size_t)N_TOK * H_DIM;
    const size_t SPC = AC * 2;
    const size_t FB  = AC * 4;
    const size_t MB  = (size_t)1 << 20;

    unsigned short* B1hi = (unsigned short*)(base);
    unsigned short* B1lo = (unsigned short*)(base + SPC);
    unsigned short* B2hi = (unsigned short*)(base + FB);
    unsigned short* B2lo = (unsigned short*)(base + FB + SPC);
    unsigned short* Qhi  = (unsigned short*)(base + 2 * FB);
    unsigned short* Qlo  = (unsigned short*)(base + 2 * FB + SPC);
    unsigned short* Khi  = (unsigned short*)(base + 3 * FB);
    unsigned short* Klo  = (unsigned short*)(base + 3 * FB + SPC);
    unsigned short* VThi = (unsigned short*)(base + 4 * FB);
    unsigned short* VTlo = (unsigned short*)(base + 4 * FB + SPC);
    float* h1f = (float*)(base + 3 * FB);

    char* wp = base + 5 * FB;
    unsigned short* We1hi = (unsigned short*)(wp);
    unsigned short* We1lo = (unsigned short*)(wp + 2 * MB);
    unsigned short* We2hi = (unsigned short*)(wp + 4 * MB);
    unsigned short* We2lo = (unsigned short*)(wp + 6 * MB);
    unsigned short* QKVhi = (unsigned short*)(wp + 8 * MB);
    unsigned short* QKVlo = (unsigned short*)(wp + 14 * MB);
    unsigned short* Wohi  = (unsigned short*)(wp + 20 * MB);
    unsigned short* Wolo  = (unsigned short*)(wp + 22 * MB);
    unsigned short* Wr1hi = (unsigned short*)(wp + 24 * MB);
    unsigned short* Wr1lo = (unsigned short*)(wp + 26 * MB);
    char* smalls = wp + 28 * MB;
    float* wr2t    = (float*)smalls;
    float* seas24  = wr2t + 8192;
    float* seasons = seas24 + 6144;

    const size_t NEC = (size_t)N_TOK * E_EXP * CAPV;
    const float QSCALE = 0.08838834764831845f;

    float* OP = out;
    float* ML = out + (size_t)2 * 16 * 2048 * 128;

    dim3 blk(256), blk512(512);

    WBatch wb;
    wb.src[0] = We1; wb.dh[0] = We1hi; wb.dl[0] = We1lo;
    wb.src[1] = We2; wb.dh[1] = We2hi; wb.dl[1] = We2lo;
    wb.src[2] = Wq;  wb.dh[2] = QKVhi;                        wb.dl[2] = QKVlo;
    wb.src[3] = Wk;  wb.dh[3] = QKVhi + (size_t)1024 * 1024;  wb.dl[3] = QKVlo + (size_t)1024 * 1024;
    wb.src[4] = Wv;  wb.dh[4] = QKVhi + (size_t)2048 * 1024;  wb.dl[4] = QKVlo + (size_t)2048 * 1024;
    wb.src[5] = Wo;  wb.dh[5] = Wohi;  wb.dl[5] = Wolo;
    wb.src[6] = Wr1; wb.dh[6] = Wr1hi; wb.dl[6] = Wr1lo;

    prep_wconv_k<<<5952, blk, 0, stream>>>(hid, B1hi, B1lo, Ws1, bs1, Ws2, bs2,
                                           seasons, seas24, Wr2, wr2t, wb);

    gemm_split<1, 0, 1, 0><<<256, blk512, 0, stream>>>(B1hi, B1lo, We1hi, We1lo, be1,
        nullptr, B2hi, B2lo,
        We1 + (size_t)1024 * 1024, We1 + (size_t)1025 * 1024, seasons, nullptr, nullptr, 1.f, nullptr);
    gemm_split<2, 0, 1, 0><<<256, blk512, 0, stream>>>(B2hi, B2lo, We2hi, We2lo, be2,
        nullptr, B1hi, B1lo, nullptr, nullptr, nullptr, pos, seas24, 1.f, nullptr);

    gemm_qkv<<<768 + NFILLQ, blk512, 0, stream>>>(B1hi, B1lo, QKVhi, QKVlo, bq, bk, bv,
                                                  Qhi, Qlo, Khi, Klo, VThi, VTlo, QSCALE, out);

    attn_mfma_k<<<1024, blk, 0, stream>>>(Qhi, Qlo, Khi, Klo, VThi, VTlo, OP, ML);
    attn_combine_k<<<2048, blk, 0, stream>>>(OP, ML, B2hi, B2lo);

    gemm_split<0, 0, 1, 32><<<256 + 32, blk512, 0, stream>>>(B2hi, B2lo, Wohi, Wolo, bo,
        nullptr, B1hi, B1lo, nullptr, nullptr, nullptr, nullptr, nullptr, 1.f, out);
    gemm_split<3, 1, 0, 0><<<256, blk512, 0, stream>>>(B1hi, B1lo, Wr1hi, Wr1lo, br1,
        h1f, nullptr, nullptr, nullptr, nullptr, nullptr, nullptr, nullptr, 1.f, nullptr);

    logits_topk_k<<<512, blk, 0, stream>>>(h1f, wr2t, br2, out);
    aux_k<<<1, blk, 0, stream>>>(out + 2 * NEC, out + 2 * NEC + (size_t)N_TOK * E_EXP);
}